// Round 2
// baseline (305.700 us; speedup 1.0000x reference)
//
#include <hip/hip_runtime.h>
#include <math.h>

#define NN 4
#define TMAX 20
#define EPS 1e-6f
#define POST_MULT 2.0f
#define KT 4  // t's per block (pipelined)

// Native vector type usable with __builtin_nontemporal_store (HIP's float4 is
// a class and is rejected by the builtin).
typedef float vfloat4 __attribute__((ext_vector_type(4)));

// ---------------------------------------------------------------------------
// Fused kernel, KT=4 t's per block, software-pipelined.
//   Phase 1 (wave 0, lanes 0..63 = 4 groups x 16 lanes): shuffle-based
//     Sinkhorn for all 4 t's in parallel (xor masks 1/2/4/8 stay inside each
//     16-lane group), results to 4x24 floats of LDS.
//   All waves issue the k=0 global loads BEFORE the barrier (independent of
//     LDS), overlapping HBM latency with the Sinkhorn chain.
//   Phase 2: depth-2 software pipeline over the 4 t's — loads for t(k+1)
//     issue before compute+store of t(k). Each thread gets 4 pipelined trips
//     instead of the previous single trip (the round-1 kernel was
//     latency-bound at 2.4 TB/s with one trip per thread).
// Grid: ceil(T/KT) blocks. NT stores keep the 168 MB output stream out of
// L2/L3 so the inputs stay L3-resident (FETCH_SIZE showed ~50% L3 hit).
// ---------------------------------------------------------------------------
__global__ __launch_bounds__(256) void fused_kernel(
    const float* __restrict__ x,          // (T, 4, C)
    const float* __restrict__ f_out,      // (T, C)
    const float* __restrict__ mix,        // (T, 24)
    const float* __restrict__ invr,       // (T,)
    const float* __restrict__ alpha_pre,  // (1,)
    const float* __restrict__ alpha_post, // (1,)
    const float* __restrict__ alpha_res,  // (1,)
    const float* __restrict__ bias,       // (24,)
    float* __restrict__ y_pre,            // (T, C)
    float* __restrict__ out,              // (T, 4, C)
    int C, int T)
{
    __shared__ float sm[KT][24];

    const int t0  = blockIdx.x * KT;
    const int tid = threadIdx.x;

    // --- Phase 1: coefficients for KT t's (wave 0, 16 lanes per t) ---
    if (tid < 16 * KT) {
        const int g    = tid >> 4;   // which t within the chunk
        const int lane = tid & 15;   // flat index i*4+j
        const int t    = t0 + g;
        if (t < T) {
            const float ir = invr[t];

            float r = mix[t * 24 + 8 + lane] * ir * alpha_res[0] + bias[8 + lane];
            float m = r;
            m = fmaxf(m, __shfl_xor(m, 1));
            m = fmaxf(m, __shfl_xor(m, 2));
            r = __expf(r - m);
            #pragma unroll
            for (int it = 0; it < TMAX; ++it) {
                float rs = r;                   // row sum (over j)
                rs += __shfl_xor(rs, 1);
                rs += __shfl_xor(rs, 2);
                r = r / (rs + EPS);
                float cs = r;                   // col sum (over i)
                cs += __shfl_xor(cs, 4);
                cs += __shfl_xor(cs, 8);
                r = r / (cs + EPS);
            }
            sm[g][8 + lane] = r;

            if (lane < 8) {
                const float a = (lane < NN) ? alpha_pre[0] : alpha_post[0];
                const float z = mix[t * 24 + lane] * ir * a + bias[lane];
                float sg = 1.0f / (1.0f + __expf(-z));
                if (lane >= NN) sg *= POST_MULT;
                sm[g][lane] = sg;
            }
        }
    }

    const int NV = C >> 2;

    for (int v = tid; v < NV; v += blockDim.x) {
        // Prefetch k=0 before the barrier (independent of sm): waves 1..3
        // get their first HBM loads in flight while wave 0 runs Sinkhorn.
        vfloat4 xA[NN], fA;
        {
            const vfloat4* xp = (const vfloat4*)(x + (size_t)t0 * NN * C);
            const vfloat4* fp = (const vfloat4*)(f_out + (size_t)t0 * C);
            #pragma unroll
            for (int n = 0; n < NN; ++n) xA[n] = xp[n * NV + v];
            fA = fp[v];
        }
        __syncthreads();

        #pragma unroll
        for (int k = 0; k < KT; ++k) {
            const int t = t0 + k;
            if (t >= T) break;

            // Issue next-t loads before this t's compute/store (depth-2 SW pipe)
            vfloat4 xB[NN], fB;
            const bool have_next = (k + 1 < KT) && (t + 1 < T);
            if (have_next) {
                const vfloat4* xp = (const vfloat4*)(x + (size_t)(t + 1) * NN * C);
                const vfloat4* fp = (const vfloat4*)(f_out + (size_t)(t + 1) * C);
                #pragma unroll
                for (int n = 0; n < NN; ++n) xB[n] = xp[n * NV + v];
                fB = fp[v];
            }

            // Coefficients for this t (uniform LDS broadcast reads)
            const float hp0 = sm[k][0], hp1 = sm[k][1], hp2 = sm[k][2], hp3 = sm[k][3];
            const float hq[NN] = {sm[k][4], sm[k][5], sm[k][6], sm[k][7]};
            float hr[NN][NN];
            #pragma unroll
            for (int j = 0; j < NN; ++j)
                #pragma unroll
                for (int i = 0; i < NN; ++i)
                    hr[j][i] = sm[k][8 + j * 4 + i];

            vfloat4* yp4 = (vfloat4*)(y_pre + (size_t)t * C);
            vfloat4* o4  = (vfloat4*)(out + (size_t)t * NN * C);

            // y_pre = sum_n h_pre[n] * x[n]
            vfloat4 yv = hp0 * xA[0] + hp1 * xA[1] + hp2 * xA[2] + hp3 * xA[3];
            __builtin_nontemporal_store(yv, &yp4[v]);

            // out[j] = sum_i hr[j][i] * x[i] + h_post[j] * f_out
            #pragma unroll
            for (int j = 0; j < NN; ++j) {
                vfloat4 ov = hq[j] * fA;
                #pragma unroll
                for (int i = 0; i < NN; ++i) ov += hr[j][i] * xA[i];
                __builtin_nontemporal_store(ov, &o4[j * NV + v]);
            }

            if (have_next) {
                #pragma unroll
                for (int n = 0; n < NN; ++n) xA[n] = xB[n];
                fA = fB;
            }
        }
    }
}

extern "C" void kernel_launch(void* const* d_in, const int* in_sizes, int n_in,
                              void* d_out, int out_size, void* d_ws, size_t ws_size,
                              hipStream_t stream) {
    const float* x          = (const float*)d_in[0];
    const float* f_out      = (const float*)d_in[1];
    const float* mix        = (const float*)d_in[2];
    const float* invr       = (const float*)d_in[3];
    const float* alpha_pre  = (const float*)d_in[4];
    const float* alpha_post = (const float*)d_in[5];
    const float* alpha_res  = (const float*)d_in[6];
    const float* bias       = (const float*)d_in[7];

    const int T = in_sizes[3];               // invr is (T,)
    const int C = in_sizes[1] / T;           // f_out is (T, C)

    float* y_pre = (float*)d_out;                   // (T, C)
    float* out   = (float*)d_out + (size_t)T * C;   // (T, N, C)
    (void)d_ws; (void)ws_size;                      // no workspace needed

    const int grid = (T + KT - 1) / KT;
    fused_kernel<<<grid, 256, 0, stream>>>(x, f_out, mix, invr, alpha_pre,
                                           alpha_post, alpha_res, bias,
                                           y_pre, out, C, T);
}